// Round 4
// baseline (70.113 us; speedup 1.0000x reference)
//
#include <hip/hip_runtime.h>
#include <math.h>

// x: (1,3,48,48,48) fp32. out[v] = sum(g*wd*p)/sum(g*wd); all normalizations
// cancel. Weight folded into one exp2: w = exp2(d^2*C2 + LG[i]+LG[j]+LG[l]).
//   C2 = -1/(2*0.8^2)*log2(e); LG = log2 of sigma=1.1 gaussian taps.
// Round 4: 4 outputs/thread along w. Per (i,j) row: 3 aligned float4 loads
// covering [w0-4, w0+8) + branchless replicate-pad selects. Cuts VMEM insts
// per output 125 -> 18.75 (theory: kernel is L1-transaction bound, which is
// why wave-count changes were neutral).

__global__ __launch_bounds__(64)
void bilateral3d(const float* __restrict__ x, float* __restrict__ out) {
    constexpr float C2 = -1.1271055f;   // -0.78125 * log2(e)
    constexpr float L0 = -2.3846116f;   // -4/2.42 * log2(e)
    constexpr float L1 = -0.5961529f;   // L0/4
    const float LGc[5] = {L0, L1, 0.0f, L1, L0};  // constant-indexed only

    const int q   = blockIdx.x * 64 + threadIdx.x;  // 82944 w-quads total
    const int qw  = q % 12;            // which quad in the row
    const int t   = q / 12;
    const int qh  = t % 48;
    const int qcd = t / 48;            // c*48 + d
    const int w0  = qw * 4;
    const int d0  = qcd % 48;
    const int dz  = qcd - d0;

    const bool left  = (qw == 0);
    const bool right = (qw == 11);
    const int a_off = left  ? 0  : (w0 - 4);   // aligned left float4
    const int c_off = right ? 44 : (w0 + 4);   // aligned right float4

    // clamped h offsets (replicate pad)
    int hh[5];
    #pragma unroll
    for (int k = 0; k < 5; ++k) {
        int b = qh + k - 2; hh[k] = b < 0 ? 0 : (b > 47 ? 47 : b);
    }

    const int crow = (qcd * 48 + qh) * 48;      // center row base
    const float4 c4 = *(const float4*)(x + crow + w0);
    const float ctr[4] = {c4.x, c4.y, c4.z, c4.w};

    float num[4] = {0.f, 0.f, 0.f, 0.f};
    float den[4] = {0.f, 0.f, 0.f, 0.f};

    #pragma unroll 1   // keep body ~6KB (I-cache); j/l/o fully unrolled
    for (int i = 0; i < 5; ++i) {
        int a = d0 + i - 2; a = a < 0 ? 0 : (a > 47 ? 47 : a);
        const int sbase = (dz + a) * 2304;
        const float Li = (i == 2) ? 0.0f : ((i == 1 || i == 3) ? L1 : L0);
        #pragma unroll
        for (int j = 0; j < 5; ++j) {
            const int rbase = sbase + hh[j] * 48;
            const float4 A = *(const float4*)(x + rbase + a_off);
            const float4 B = *(const float4*)(x + rbase + w0);
            const float4 C = *(const float4*)(x + rbase + c_off);
            // 8-float window [w0-2 .. w0+5] with replicate-pad in w
            float win[8];
            win[0] = left  ? B.x : A.z;
            win[1] = left  ? B.x : A.w;
            win[2] = B.x; win[3] = B.y; win[4] = B.z; win[5] = B.w;
            win[6] = right ? B.w : C.x;
            win[7] = right ? B.w : C.y;
            const float Lij = Li + LGc[j];
            #pragma unroll
            for (int l = 0; l < 5; ++l) {
                const float Lc = Lij + LGc[l];
                #pragma unroll
                for (int o = 0; o < 4; ++o) {
                    const float p   = win[o + l];
                    const float dlt = p - ctr[o];
                    const float e   = __builtin_amdgcn_exp2f(fmaf(dlt * dlt, C2, Lc));
                    num[o] = fmaf(e, p, num[o]);
                    den[o] += e;
                }
            }
        }
    }

    float4 o4;
    o4.x = num[0] / den[0];
    o4.y = num[1] / den[1];
    o4.z = num[2] / den[2];
    o4.w = num[3] / den[3];
    *(float4*)(out + crow + w0) = o4;
}

extern "C" void kernel_launch(void* const* d_in, const int* in_sizes, int n_in,
                              void* d_out, int out_size, void* d_ws, size_t ws_size,
                              hipStream_t stream) {
    const float* x = (const float*)d_in[0];
    float* out = (float*)d_out;
    // 82944 threads (one per w-quad) in 1296 single-wave blocks -> ~5/CU, balanced
    hipLaunchKernelGGL(bilateral3d, dim3(1296), dim3(64), 0, stream, x, out);
}

// Round 5
// 65.638 us; speedup vs baseline: 1.0682x; 1.0682x over previous
//
#include <hip/hip_runtime.h>
#include <math.h>

// x: (1,3,48,48,48) fp32. out[v] = sum(g*wd*p)/sum(g*wd); normalizations cancel.
// Weight folded into one exp2: w = exp2(d^2*C2 + LG[i]+LG[j]+LG[l]).
// Round 5: 2 outputs/thread along w (float2 windows). Rationale:
//  - R1-R3: scalar loads -> per-CU L1/TD pipe saturates at ~2 waves/SIMD (plateau 24us)
//  - R4: 4 out/thread -> 1.27 waves/SIMD -> latency-bound regression
//  - 2 out/thread: 2592 waves = 2.53 waves/SIMD (above knee) AND 3.3x fewer
//    loads/output than R2 with contiguous float2 accesses.

__global__ __launch_bounds__(64)
void bilateral3d(const float* __restrict__ x, float* __restrict__ out) {
    constexpr float C2 = -1.1271055f;   // -0.78125 * log2(e)
    constexpr float L0 = -2.3846116f;   // -4/2.42 * log2(e)
    constexpr float L1 = -0.5961529f;   // L0/4
    const float LGc[5] = {L0, L1, 0.0f, L1, L0};

    const int P   = blockIdx.x * 64 + threadIdx.x;  // pair id, 0..165887
    const int pw  = P % 24;
    const int t   = P / 24;
    const int ph  = t % 48;
    const int pcd = t / 48;             // c*48 + d
    const int w0  = pw * 2;
    const int d0  = pcd % 48;
    const int dz  = pcd - d0;

    const bool left  = (pw == 0);
    const bool right = (pw == 23);
    const int a_off = left  ? 0 : (w0 - 2);  // 8B-aligned, in-bounds
    const int c_off = right ? 0 : (w0 + 2);  // dummy 0 when discarded

    int hh[5];
    #pragma unroll
    for (int k = 0; k < 5; ++k) {
        int b = ph + k - 2; hh[k] = b < 0 ? 0 : (b > 47 ? 47 : b);
    }

    const int crow = (pcd * 48 + ph) * 48;
    const float2 c2v = *(const float2*)(x + crow + w0);
    const float ctr[2] = {c2v.x, c2v.y};

    float num[2] = {0.f, 0.f};
    float den[2] = {0.f, 0.f};

    #pragma unroll 1   // keep body small; j/l/o fully unrolled
    for (int i = 0; i < 5; ++i) {
        int a = d0 + i - 2; a = a < 0 ? 0 : (a > 47 ? 47 : a);
        const int sbase = (dz + a) * 2304;
        const float Li = (i == 2) ? 0.0f : ((i == 1 || i == 3) ? L1 : L0);
        #pragma unroll
        for (int j = 0; j < 5; ++j) {
            const int rbase = sbase + hh[j] * 48;
            const float2 A = *(const float2*)(x + rbase + a_off);
            const float2 B = *(const float2*)(x + rbase + w0);
            const float2 C = *(const float2*)(x + rbase + c_off);
            // 6-float window [w0-2 .. w0+3], replicate-pad in w
            float win[6];
            win[0] = left  ? B.x : A.x;
            win[1] = left  ? B.x : A.y;
            win[2] = B.x; win[3] = B.y;
            win[4] = right ? B.y : C.x;
            win[5] = right ? B.y : C.y;
            const float Lij = Li + LGc[j];
            #pragma unroll
            for (int l = 0; l < 5; ++l) {
                const float Lc = Lij + LGc[l];
                #pragma unroll
                for (int o = 0; o < 2; ++o) {
                    const float p   = win[o + l];
                    const float dlt = p - ctr[o];
                    const float e   = __builtin_amdgcn_exp2f(fmaf(dlt * dlt, C2, Lc));
                    num[o] = fmaf(e, p, num[o]);
                    den[o] += e;
                }
            }
        }
    }

    float2 o2;
    o2.x = num[0] / den[0];
    o2.y = num[1] / den[1];
    *(float2*)(out + crow + w0) = o2;
}

extern "C" void kernel_launch(void* const* d_in, const int* in_sizes, int n_in,
                              void* d_out, int out_size, void* d_ws, size_t ws_size,
                              hipStream_t stream) {
    const float* x = (const float*)d_in[0];
    float* out = (float*)d_out;
    // 165888 threads (one per w-pair) in 2592 single-wave blocks
    // -> 2.53 waves/SIMD, balanced across 256 CUs
    hipLaunchKernelGGL(bilateral3d, dim3(2592), dim3(64), 0, stream, x, out);
}